// Round 7
// baseline (415.561 us; speedup 1.0000x reference)
//
#include <hip/hip_runtime.h>
#include <math.h>

#define B_ 512
#define N_ 62
#define V_ (B_ * N_)      // 31744
#define TOPK_ 8

typedef __attribute__((ext_vector_type(8))) short bf16x8;
typedef __attribute__((ext_vector_type(4))) float f32x4;

// round-to-nearest-even f32 -> bf16 bits
__device__ __forceinline__ unsigned short bf16rn(float f) {
    unsigned int u = __float_as_uint(f);
    unsigned int r = (u + 0x7fffu + ((u >> 16) & 1u)) >> 16;
    return (unsigned short)r;
}
__device__ __forceinline__ float bf16tof(unsigned short h) {
    return __uint_as_float(((unsigned int)h) << 16);
}

__device__ __forceinline__ void gload16(const void* g, void* l) {
    __builtin_amdgcn_global_load_lds(
        (const __attribute__((address_space(1))) unsigned int*)g,
        (__attribute__((address_space(3))) unsigned int*)l, 16, 0, 0);
}

// ---------------------------------------------------------------------------
// Stage 1: S[b,n,m] = tanh( (einsum('bnct,t',x,W1) @ W2) @ V_sp + b_sp )
// Also emits A2 = bf16(x) (fused split_hi: x is only read once).
// ---------------------------------------------------------------------------
__global__ __launch_bounds__(64) void spatial_S(
    const float* __restrict__ x, const float* __restrict__ W1,
    const float* __restrict__ W2, const float* __restrict__ bsp,
    const float* __restrict__ Vsp, float* __restrict__ S,
    unsigned short* __restrict__ A2)
{
    int blk = blockIdx.x;            // b*62 + n
    int n = blk % N_;
    int lane = threadIdx.x;          // 0..63
    const float* xr = x + (size_t)blk * 512;   // [8][64] row
    float w1 = W1[lane];

    float y[8];
#pragma unroll
    for (int c = 0; c < 8; ++c) {
        float xv = xr[c * 64 + lane];
        A2[(size_t)blk * 512 + c * 64 + lane] = bf16rn(xv);
        float p = xv * w1;
#pragma unroll
        for (int off = 32; off; off >>= 1) p += __shfl_xor(p, off);
        y[c] = p;
    }

    __shared__ float pr[N_];
    if (lane < N_) {
        float acc = 0.f;
#pragma unroll
        for (int c = 0; c < 8; ++c) acc += y[c] * W2[c * N_ + lane];
        pr[lane] = acc;
    }
    __syncthreads();
    if (lane < N_) {
        float acc = bsp[n * N_ + lane];
        for (int k = 0; k < N_; ++k) acc += pr[k] * Vsp[k * N_ + lane];
        S[(size_t)blk * N_ + lane] = tanhf(acc);
    }
}

// ---------------------------------------------------------------------------
// Stage 2: BatchNorm1d stats, two-stage
// ---------------------------------------------------------------------------
__global__ __launch_bounds__(256) void bn_part(
    const float* __restrict__ S, double* __restrict__ part)
{
    int n = blockIdx.x >> 4, slice = blockIdx.x & 15;
    double s = 0.0, s2 = 0.0;
    int i0 = slice * 1984;                    // 16*1984 = 31744
    for (int i = i0 + threadIdx.x; i < i0 + 1984; i += 256) {
        int b = i / N_, m = i - b * N_;
        float v = S[((size_t)b * N_ + n) * N_ + m];
        s += v; s2 += (double)v * v;
    }
    __shared__ double sh[256], sh2[256];
    sh[threadIdx.x] = s; sh2[threadIdx.x] = s2;
    __syncthreads();
    for (int off = 128; off; off >>= 1) {
        if (threadIdx.x < off) {
            sh[threadIdx.x] += sh[threadIdx.x + off];
            sh2[threadIdx.x] += sh2[threadIdx.x + off];
        }
        __syncthreads();
    }
    if (threadIdx.x == 0) {
        part[((size_t)n * 16 + slice) * 2 + 0] = sh[0];
        part[((size_t)n * 16 + slice) * 2 + 1] = sh2[0];
    }
}

__global__ __launch_bounds__(64) void bn_final(
    const double* __restrict__ part, const float* __restrict__ bnw,
    const float* __restrict__ bnb, float* __restrict__ scale,
    float* __restrict__ shift)
{
    int n = threadIdx.x;
    if (n >= N_) return;
    double s = 0.0, s2 = 0.0;
    for (int j = 0; j < 16; ++j) {
        s  += part[((size_t)n * 16 + j) * 2 + 0];
        s2 += part[((size_t)n * 16 + j) * 2 + 1];
    }
    const double cnt = (double)(B_ * N_);
    double mean = s / cnt;
    double var = s2 / cnt - mean * mean;
    float inv = (float)(1.0 / sqrt(var + 1e-5));
    scale[n] = bnw[n] * inv;
    shift[n] = bnb[n] - (float)mean * bnw[n] * inv;
}

// ---------------------------------------------------------------------------
// Stage 3: per-row top-8 -> transposed incoming-edge bitmask maskT
// ---------------------------------------------------------------------------
__global__ __launch_bounds__(64) void topk_mask(
    const float* __restrict__ S, const float* __restrict__ scale,
    const float* __restrict__ shift, unsigned long long* __restrict__ maskT)
{
    int blk = blockIdx.x;            // b*62 + n
    int b = blk / N_, n = blk - b * N_;
    int lane = threadIdx.x;
    float v = (lane < N_) ? S[(size_t)blk * N_ + lane] * scale[n] + shift[n]
                          : -INFINITY;
    bool sel = false;
#pragma unroll
    for (int k = 0; k < TOPK_; ++k) {
        float mv = v; int mi = lane;
#pragma unroll
        for (int off = 32; off; off >>= 1) {
            float ov = __shfl_xor(mv, off);
            int   oi = __shfl_xor(mi, off);
            if (ov > mv || (ov == mv && oi < mi)) { mv = ov; mi = oi; }
        }
        if (lane == mi) { sel = true; v = -INFINITY; }
    }
    unsigned long long row = __ballot(sel) | (1ull << n);  // self loop union
    if (lane < N_ && ((row >> lane) & 1ull))
        atomicOr(&maskT[(size_t)b * N_ + lane], 1ull << n);
}

__global__ __launch_bounds__(256) void zero_u64(unsigned long long* p, int n)
{
    int i = blockIdx.x * 256 + threadIdx.x;
    if (i < n) p[i] = 0ull;
}

// split fp32 [rows][512] -> bf16 [rows][1024] as [hi | lo]  (weights only)
__global__ __launch_bounds__(256) void split_pair(
    const float* __restrict__ in, unsigned short* __restrict__ out, int total4)
{
    int gid = blockIdx.x * 256 + threadIdx.x;
    if (gid >= total4) return;
    int row = gid >> 7;
    int c = (gid & 127) * 4;
    float4 v = ((const float4*)in)[gid];
    ushort4 h, l;
    float f;
    h.x = bf16rn(v.x); f = v.x - bf16tof(h.x); l.x = bf16rn(f);
    h.y = bf16rn(v.y); f = v.y - bf16tof(h.y); l.y = bf16rn(f);
    h.z = bf16rn(v.z); f = v.z - bf16tof(h.z); l.z = bf16rn(f);
    h.w = bf16rn(v.w); f = v.w - bf16tof(h.w); l.w = bf16rn(f);
    *(ushort4*)(&out[(size_t)row * 1024 + c])       = h;
    *(ushort4*)(&out[(size_t)row * 1024 + 512 + c]) = l;
}

// ---------------------------------------------------------------------------
// 2-term split GEMM:  C = Ah * (Bh + Bl)^T over virtual K = 1024
//   out Cs: [M][1024] split (hi|lo) bf16 of the f32 result.
// (verified passing in rounds 2-3, 6)
// ---------------------------------------------------------------------------
__global__ __launch_bounds__(256) void gemm_bf16(
    const unsigned short* __restrict__ Ah, const unsigned short* __restrict__ Bw,
    unsigned short* __restrict__ Cs)
{
    __shared__ __align__(16) unsigned short smem[16384];  // As 8192 + Bs 8192
    char* As = (char*)smem;            // [128 rows][128 bytes]
    char* Bs = (char*)(smem + 8192);

    int tid = threadIdx.x;
    int lane = tid & 63, w = tid >> 6;

    // XCD-bijective block swizzle: 992 = 8 * 124
    int flat = blockIdx.y * 4 + blockIdx.x;
    int swz = (flat & 7) * 124 + (flat >> 3);
    int by = swz >> 2, bx = swz & 3;
    int bm = by * 128, bn = bx * 128;

    int wr = w >> 1, wc = w & 1;

    f32x4 acc[4][4];
#pragma unroll
    for (int mf = 0; mf < 4; ++mf)
#pragma unroll
        for (int nf = 0; nf < 4; ++nf) acc[mf][nf] = (f32x4){0.f, 0.f, 0.f, 0.f};

    int srow = w * 8 + (lane >> 3);
    int kcol = (lane & 7) ^ (lane >> 3);   // inverse-swizzled global 16B col
    int ldsoff = w * 1024;

    for (int kt = 0; kt < 16; ++kt) {
        int k0 = (kt & 7) * 64;
        int bBase = (kt >> 3) * 512 + k0;  // seg0=Bh, seg1=Bl
#pragma unroll
        for (int i = 0; i < 4; ++i) {
            int row = i * 32 + srow;
            gload16(Ah + (size_t)(bm + row) * 512 + k0 + kcol * 8,
                    As + i * 4096 + ldsoff);
            gload16(Bw + (size_t)(bn + row) * 1024 + bBase + kcol * 8,
                    Bs + i * 4096 + ldsoff);
        }
        __syncthreads();

#pragma unroll
        for (int kk = 0; kk < 2; ++kk) {
            bf16x8 af[4], bfr[4];
#pragma unroll
            for (int mf = 0; mf < 4; ++mf)
                af[mf] = *(const bf16x8*)(As + (wr*64 + mf*16 + (lane&15))*128
                                             + ((kk*4 + (lane>>4)) ^ (lane&7))*16);
#pragma unroll
            for (int nf = 0; nf < 4; ++nf)
                bfr[nf] = *(const bf16x8*)(Bs + (wc*64 + nf*16 + (lane&15))*128
                                              + ((kk*4 + (lane>>4)) ^ (lane&7))*16);
#pragma unroll
            for (int mf = 0; mf < 4; ++mf)
#pragma unroll
                for (int nf = 0; nf < 4; ++nf)
                    acc[mf][nf] = __builtin_amdgcn_mfma_f32_16x16x32_bf16(
                        af[mf], bfr[nf], acc[mf][nf], 0, 0, 0);
        }
        __syncthreads();
    }

    int r0 = bm + wr * 64 + (lane >> 4) * 4;
    int c0 = bn + wc * 64 + (lane & 15);
#pragma unroll
    for (int mf = 0; mf < 4; ++mf)
#pragma unroll
        for (int nf = 0; nf < 4; ++nf)
#pragma unroll
            for (int r = 0; r < 4; ++r) {
                float v = acc[mf][nf][r];
                unsigned short h = bf16rn(v);
                unsigned short l = bf16rn(v - bf16tof(h));
                size_t row = (size_t)(r0 + mf * 16 + r);
                Cs[row * 1024 + c0 + nf * 16] = h;
                Cs[row * 1024 + 512 + c0 + nf * 16] = l;
            }
}

// ---------------------------------------------------------------------------
// MFMA GAT layer: block = batch (512 thr / 8 waves).
//  A: als/ald via vectorized bf16x8 loads, thread = (node s, 64-col slice),
//     asrc/adst staged in LDS (stride 65 -> conflict-free).
//  B: softmax -> W_att bf16 in LDS (swizzled; cols s=62,63 zeroed)
//  C: per head ch: C[62x128] = W*Xh + W*Xl via 16x16x32 MFMA; B-frag (X)
//     loaded directly from global (each element consumed by one thread).
//  APPLY=1: +bias, relu -> bf16 H[V][512].
//  APPLY=0: head-mean + bias + relu fused -> f32 out[V][128]  (final output)
// ---------------------------------------------------------------------------
template <int APPLY>
__global__ __launch_bounds__(512, 2) void gat_aggM(
    const unsigned short* __restrict__ XL,   // [V+2][1024] hi|lo
    const float* __restrict__ asrc, const float* __restrict__ adst,
    const unsigned long long* __restrict__ maskT,
    const float* __restrict__ bias,
    void* __restrict__ outp)
{
    // LDS: W_att [4][64 d][64 s] bf16 @0 (32KB, 16B groups XOR-swizzled by d&7)
    //      av @32768 (8*65 f32 = 2080B), dv @34848 (2080B)
    //      shs @36928 (256 f32), shd @37952 (256 f32)  -> 38976 total
    __shared__ __align__(16) char lds[38976];
    float* av  = (float*)(lds + 32768);
    float* dv  = (float*)(lds + 34848);
    float* shs = (float*)(lds + 36928);
    float* shd = (float*)(lds + 37952);

    int b = blockIdx.x;
    int tid = threadIdx.x;
    int lane = tid & 63, w = tid >> 6;
    const unsigned short* base = XL + (size_t)b * N_ * 1024;

    // stage attention vectors (f32, padded stride 65)
    av[(tid >> 6) * 65 + (tid & 63)] = asrc[tid];
    dv[(tid >> 6) * 65 + (tid & 63)] = adst[tid];
    __syncthreads();

    // ---- phase A: als/ald, vectorized. thread = (s = tid>>3, sl = tid&7) ----
    {
        int s = tid >> 3, sl = tid & 7;   // sl: 64-col slice; head = sl>>1
        const unsigned short* xp = base + (size_t)s * 1024 + sl * 64;
        float ps = 0.f, pd = 0.f;
        union V8 { uint4 u; unsigned short s[8]; };
#pragma unroll
        for (int g = 0; g < 8; ++g) {
            V8 vh, vl;
            vh.u = *(const uint4*)(xp + g * 8);
            vl.u = *(const uint4*)(xp + 512 + g * 8);
            const float* avp = av + sl * 65 + g * 8;
            const float* dvp = dv + sl * 65 + g * 8;
#pragma unroll
            for (int j = 0; j < 8; ++j) {
                float xv = bf16tof(vh.s[j]) + bf16tof(vl.s[j]);
                ps += xv * avp[j];
                pd += xv * dvp[j];
            }
        }
        ps += __shfl_xor(ps, 1);          // combine the two slices of a head
        pd += __shfl_xor(pd, 1);
        if ((sl & 1) == 0) {
            shs[s * 4 + (sl >> 1)] = ps;
            shd[s * 4 + (sl >> 1)] = pd;
        }
    }
    __syncthreads();

    // ---- phase B: masked softmax -> W_att (bf16, swizzled; s=62,63 -> 0) ----
    for (int t = w; t < 248; t += 8) {
        int d = t >> 2, h = t & 3;
        unsigned long long m = maskT[(size_t)b * N_ + d];
        bool valid = (lane < N_) && ((m >> lane) & 1ull);
        float a = -INFINITY;
        if (valid) {
            float raw = shs[lane * 4 + h] + shd[d * 4 + h];
            a = (raw > 0.f) ? raw : 0.2f * raw;
        }
        float mx = a;
#pragma unroll
        for (int off = 32; off; off >>= 1) mx = fmaxf(mx, __shfl_xor(mx, off));
        float ex = valid ? expf(a - mx) : 0.f;
        float sm = ex;
#pragma unroll
        for (int off = 32; off; off >>= 1) sm += __shfl_xor(sm, off);
        float wv = valid ? ex / sm : 0.f;
        int addr = h * 8192 + d * 128
                 + (((lane >> 3) ^ (d & 7)) << 4) + ((lane & 7) << 1);
        *(unsigned short*)(lds + addr) = bf16rn(wv);
    }
    __syncthreads();   // W ready; no LDS writes after this point

    int cc = lane & 15, lh = lane >> 4;

    union U8 { unsigned short s[8]; bf16x8 v; };

    f32x4 macc[4];
    if (APPLY == 0) {
#pragma unroll
        for (int mf = 0; mf < 4; ++mf) macc[mf] = (f32x4){0.f, 0.f, 0.f, 0.f};
    }

#pragma unroll
    for (int ch = 0; ch < 4; ++ch) {     // chunk == head
        f32x4 acc[4];
#pragma unroll
        for (int mf = 0; mf < 4; ++mf) acc[mf] = (f32x4){0.f, 0.f, 0.f, 0.f};

        // this thread's column c and its s-rows lh*8..+7 (+32 for kk=1)
        const unsigned short* xp = base + (size_t)(lh * 8) * 1024
                                        + ch * 128 + w * 16 + cc;
#pragma unroll
        for (int kk = 0; kk < 2; ++kk) {
            U8 bh, bl;
#pragma unroll
            for (int j = 0; j < 8; ++j) {
                size_t o = (size_t)(kk * 32 + j) * 1024;
                bh.s[j] = xp[o];            // hi
                bl.s[j] = xp[o + 512];      // lo
            }
            bf16x8 af[4];
#pragma unroll
            for (int mf = 0; mf < 4; ++mf)
                af[mf] = *(const bf16x8*)(lds + ch * 8192
                              + (mf * 16 + cc) * 128
                              + (((kk * 4 + lh) ^ (cc & 7)) << 4));
#pragma unroll
            for (int mf = 0; mf < 4; ++mf) {
                acc[mf] = __builtin_amdgcn_mfma_f32_16x16x32_bf16(
                    af[mf], bh.v, acc[mf], 0, 0, 0);
                acc[mf] = __builtin_amdgcn_mfma_f32_16x16x32_bf16(
                    af[mf], bl.v, acc[mf], 0, 0, 0);
            }
        }

        if (APPLY == 1) {
            int c = ch * 128 + w * 16 + cc;
            float bc = bias[c];
            unsigned short* H = (unsigned short*)outp;
#pragma unroll
            for (int mf = 0; mf < 4; ++mf)
#pragma unroll
                for (int r = 0; r < 4; ++r) {
                    int d = mf * 16 + lh * 4 + r;
                    if (d < N_) {
                        float v = acc[mf][r] + bc;
                        v = v > 0.f ? v : 0.f;
                        H[(size_t)(b * N_ + d) * 512 + c] = bf16rn(v);
                    }
                }
        } else {
#pragma unroll
            for (int mf = 0; mf < 4; ++mf) macc[mf] += acc[mf];
        }
    }

    if (APPLY == 0) {
        // head-mean + bias + relu -> final f32 output [V][128]
        int c = w * 16 + cc;
        float bc = bias[c];
        float* outF = (float*)outp;
#pragma unroll
        for (int mf = 0; mf < 4; ++mf)
#pragma unroll
            for (int r = 0; r < 4; ++r) {
                int d = mf * 16 + lh * 4 + r;
                if (d < N_) {
                    float v = macc[mf][r] * 0.25f + bc;
                    outF[(size_t)(b * N_ + d) * 128 + c] = v > 0.f ? v : 0.f;
                }
            }
    }
}

// ---------------------------------------------------------------------------
extern "C" void kernel_launch(void* const* d_in, const int* in_sizes, int n_in,
                              void* d_out, int out_size, void* d_ws, size_t ws_size,
                              hipStream_t stream)
{
    const float* x    = (const float*)d_in[0];
    const float* W1   = (const float*)d_in[2];
    const float* W2   = (const float*)d_in[3];
    const float* bsp  = (const float*)d_in[4];
    const float* Vsp  = (const float*)d_in[5];
    const float* bnw  = (const float*)d_in[6];
    const float* bnb  = (const float*)d_in[7];
    const float* g1w  = (const float*)d_in[8];
    const float* g1as = (const float*)d_in[9];
    const float* g1ad = (const float*)d_in[10];
    const float* g1b  = (const float*)d_in[11];
    const float* g2w  = (const float*)d_in[12];
    const float* g2as = (const float*)d_in[13];
    const float* g2ad = (const float*)d_in[14];
    const float* g2b  = (const float*)d_in[15];
    float* out = (float*)d_out;

    char* ws = (char*)d_ws;
    size_t off = 0;
    auto alloc = [&](size_t bytes) -> void* {
        void* p = ws + off;
        off += (bytes + 255) & ~(size_t)255;
        return p;
    };
    float* S      = (float*)alloc((size_t)V_ * N_ * 4);          // 7.9 MB
    float* scale  = (float*)alloc(N_ * 4);
    float* shift  = (float*)alloc(N_ * 4);
    double* part  = (double*)alloc((size_t)N_ * 16 * 2 * 8);
    unsigned long long* maskT = (unsigned long long*)alloc((size_t)V_ * 8);
    unsigned short* A2  = (unsigned short*)alloc((size_t)V_ * 512 * 2);      // 32.5 MB
    unsigned short* Bw1 = (unsigned short*)alloc((size_t)512 * 1024 * 2);    // 1 MB
    unsigned short* Bw2 = (unsigned short*)alloc((size_t)512 * 1024 * 2);    // 1 MB
    unsigned short* XL  = (unsigned short*)alloc((size_t)(V_ + 2) * 1024 * 2); // 65 MB (+slack)
    unsigned short* H1  = (unsigned short*)alloc((size_t)V_ * 512 * 2);      // 32.5 MB

    zero_u64<<<(V_ + 255) / 256, 256, 0, stream>>>(maskT, V_);
    spatial_S<<<V_, 64, 0, stream>>>(x, W1, W2, bsp, Vsp, S, A2);
    bn_part<<<N_ * 16, 256, 0, stream>>>(S, part);
    bn_final<<<1, 64, 0, stream>>>(part, bnw, bnb, scale, shift);
    topk_mask<<<V_, 64, 0, stream>>>(S, scale, shift, maskT);

    split_pair<<<(512 * 128 + 255) / 256, 256, 0, stream>>>(g1w, Bw1, 512 * 128);
    split_pair<<<(512 * 128 + 255) / 256, 256, 0, stream>>>(g2w, Bw2, 512 * 128);

    dim3 gg(4, 248);
    gemm_bf16<<<gg, 256, 0, stream>>>(A2, Bw1, XL);
    gat_aggM<1><<<B_, 512, 0, stream>>>(XL, g1as, g1ad, maskT, g1b, H1);

    gemm_bf16<<<gg, 256, 0, stream>>>(H1, Bw2, XL);
    gat_aggM<0><<<B_, 512, 0, stream>>>(XL, g2as, g2ad, maskT, g2b, out);
}

// Round 8
// 412.315 us; speedup vs baseline: 1.0079x; 1.0079x over previous
//
#include <hip/hip_runtime.h>
#include <math.h>

#define B_ 512
#define N_ 62
#define V_ (B_ * N_)      // 31744
#define TOPK_ 8

typedef __attribute__((ext_vector_type(8))) short bf16x8;
typedef __attribute__((ext_vector_type(4))) float f32x4;

// round-to-nearest-even f32 -> bf16 bits
__device__ __forceinline__ unsigned short bf16rn(float f) {
    unsigned int u = __float_as_uint(f);
    unsigned int r = (u + 0x7fffu + ((u >> 16) & 1u)) >> 16;
    return (unsigned short)r;
}
__device__ __forceinline__ float bf16tof(unsigned short h) {
    return __uint_as_float(((unsigned int)h) << 16);
}

__device__ __forceinline__ void gload16(const void* g, void* l) {
    __builtin_amdgcn_global_load_lds(
        (const __attribute__((address_space(1))) unsigned int*)g,
        (__attribute__((address_space(3))) unsigned int*)l, 16, 0, 0);
}

// ---------------------------------------------------------------------------
// Stage 1: S[b,n,m] = tanh( (einsum('bnct,t',x,W1) @ W2) @ V_sp + b_sp )
// Also emits A2 = bf16(x). 4 nodes per block (wave = node).
// ---------------------------------------------------------------------------
__global__ __launch_bounds__(256) void spatial_S(
    const float* __restrict__ x, const float* __restrict__ W1,
    const float* __restrict__ W2, const float* __restrict__ bsp,
    const float* __restrict__ Vsp, float* __restrict__ S,
    unsigned short* __restrict__ A2)
{
    int w = threadIdx.x >> 6, lane = threadIdx.x & 63;
    int blk = blockIdx.x * 4 + w;    // b*62 + n
    int n = blk % N_;
    const float* xr = x + (size_t)blk * 512;   // [8][64] row
    float w1 = W1[lane];

    float y[8];
#pragma unroll
    for (int c = 0; c < 8; ++c) {
        float xv = xr[c * 64 + lane];
        A2[(size_t)blk * 512 + c * 64 + lane] = bf16rn(xv);
        float p = xv * w1;
#pragma unroll
        for (int off = 32; off; off >>= 1) p += __shfl_xor(p, off);
        y[c] = p;
    }

    __shared__ float pr[4][N_];
    if (lane < N_) {
        float acc = 0.f;
#pragma unroll
        for (int c = 0; c < 8; ++c) acc += y[c] * W2[c * N_ + lane];
        pr[w][lane] = acc;
    }
    __syncthreads();
    if (lane < N_) {
        float acc = bsp[n * N_ + lane];
        for (int k = 0; k < N_; ++k) acc += pr[w][k] * Vsp[k * N_ + lane];
        S[(size_t)blk * N_ + lane] = tanhf(acc);
    }
}

// ---------------------------------------------------------------------------
// Stage 2: BatchNorm1d stats, two-stage
// ---------------------------------------------------------------------------
__global__ __launch_bounds__(256) void bn_part(
    const float* __restrict__ S, double* __restrict__ part)
{
    int n = blockIdx.x >> 4, slice = blockIdx.x & 15;
    double s = 0.0, s2 = 0.0;
    int i0 = slice * 1984;                    // 16*1984 = 31744
    for (int i = i0 + threadIdx.x; i < i0 + 1984; i += 256) {
        int b = i / N_, m = i - b * N_;
        float v = S[((size_t)b * N_ + n) * N_ + m];
        s += v; s2 += (double)v * v;
    }
    __shared__ double sh[256], sh2[256];
    sh[threadIdx.x] = s; sh2[threadIdx.x] = s2;
    __syncthreads();
    for (int off = 128; off; off >>= 1) {
        if (threadIdx.x < off) {
            sh[threadIdx.x] += sh[threadIdx.x + off];
            sh2[threadIdx.x] += sh2[threadIdx.x + off];
        }
        __syncthreads();
    }
    if (threadIdx.x == 0) {
        part[((size_t)n * 16 + slice) * 2 + 0] = sh[0];
        part[((size_t)n * 16 + slice) * 2 + 1] = sh2[0];
    }
}

__global__ __launch_bounds__(64) void bn_final(
    const double* __restrict__ part, const float* __restrict__ bnw,
    const float* __restrict__ bnb, float* __restrict__ scale,
    float* __restrict__ shift)
{
    int n = threadIdx.x;
    if (n >= N_) return;
    double s = 0.0, s2 = 0.0;
    for (int j = 0; j < 16; ++j) {
        s  += part[((size_t)n * 16 + j) * 2 + 0];
        s2 += part[((size_t)n * 16 + j) * 2 + 1];
    }
    const double cnt = (double)(B_ * N_);
    double mean = s / cnt;
    double var = s2 / cnt - mean * mean;
    float inv = (float)(1.0 / sqrt(var + 1e-5));
    scale[n] = bnw[n] * inv;
    shift[n] = bnb[n] - (float)mean * bnw[n] * inv;
}

// ---------------------------------------------------------------------------
// Stage 3: per-row top-8 -> transposed incoming-edge bitmask maskT
// ---------------------------------------------------------------------------
__global__ __launch_bounds__(64) void topk_mask(
    const float* __restrict__ S, const float* __restrict__ scale,
    const float* __restrict__ shift, unsigned long long* __restrict__ maskT)
{
    int blk = blockIdx.x;            // b*62 + n
    int b = blk / N_, n = blk - b * N_;
    int lane = threadIdx.x;
    float v = (lane < N_) ? S[(size_t)blk * N_ + lane] * scale[n] + shift[n]
                          : -INFINITY;
    bool sel = false;
#pragma unroll
    for (int k = 0; k < TOPK_; ++k) {
        float mv = v; int mi = lane;
#pragma unroll
        for (int off = 32; off; off >>= 1) {
            float ov = __shfl_xor(mv, off);
            int   oi = __shfl_xor(mi, off);
            if (ov > mv || (ov == mv && oi < mi)) { mv = ov; mi = oi; }
        }
        if (lane == mi) { sel = true; v = -INFINITY; }
    }
    unsigned long long row = __ballot(sel) | (1ull << n);  // self loop union
    if (lane < N_ && ((row >> lane) & 1ull))
        atomicOr(&maskT[(size_t)b * N_ + lane], 1ull << n);
}

__global__ __launch_bounds__(256) void zero_u64(unsigned long long* p, int n)
{
    int i = blockIdx.x * 256 + threadIdx.x;
    if (i < n) p[i] = 0ull;
}

// split fp32 [rows][512] -> bf16 [rows][1024] as [hi | lo]  (weights only)
__global__ __launch_bounds__(256) void split_pair(
    const float* __restrict__ in, unsigned short* __restrict__ out, int total4)
{
    int gid = blockIdx.x * 256 + threadIdx.x;
    if (gid >= total4) return;
    int row = gid >> 7;
    int c = (gid & 127) * 4;
    float4 v = ((const float4*)in)[gid];
    ushort4 h, l;
    float f;
    h.x = bf16rn(v.x); f = v.x - bf16tof(h.x); l.x = bf16rn(f);
    h.y = bf16rn(v.y); f = v.y - bf16tof(h.y); l.y = bf16rn(f);
    h.z = bf16rn(v.z); f = v.z - bf16tof(h.z); l.z = bf16rn(f);
    h.w = bf16rn(v.w); f = v.w - bf16tof(h.w); l.w = bf16rn(f);
    *(ushort4*)(&out[(size_t)row * 1024 + c])       = h;
    *(ushort4*)(&out[(size_t)row * 1024 + 512 + c]) = l;
}

// ---------------------------------------------------------------------------
// 2-term split GEMM:  C = Ah * (Bh + Bl)^T over virtual K = 1024
//   out Cs: [M][1024] split (hi|lo) bf16 of the f32 result.
// (verified passing in rounds 2-3, 6, 7)
// ---------------------------------------------------------------------------
__global__ __launch_bounds__(256) void gemm_bf16(
    const unsigned short* __restrict__ Ah, const unsigned short* __restrict__ Bw,
    unsigned short* __restrict__ Cs)
{
    __shared__ __align__(16) unsigned short smem[16384];  // As 8192 + Bs 8192
    char* As = (char*)smem;            // [128 rows][128 bytes]
    char* Bs = (char*)(smem + 8192);

    int tid = threadIdx.x;
    int lane = tid & 63, w = tid >> 6;

    // XCD-bijective block swizzle: 992 = 8 * 124
    int flat = blockIdx.y * 4 + blockIdx.x;
    int swz = (flat & 7) * 124 + (flat >> 3);
    int by = swz >> 2, bx = swz & 3;
    int bm = by * 128, bn = bx * 128;

    int wr = w >> 1, wc = w & 1;

    f32x4 acc[4][4];
#pragma unroll
    for (int mf = 0; mf < 4; ++mf)
#pragma unroll
        for (int nf = 0; nf < 4; ++nf) acc[mf][nf] = (f32x4){0.f, 0.f, 0.f, 0.f};

    int srow = w * 8 + (lane >> 3);
    int kcol = (lane & 7) ^ (lane >> 3);   // inverse-swizzled global 16B col
    int ldsoff = w * 1024;

    for (int kt = 0; kt < 16; ++kt) {
        int k0 = (kt & 7) * 64;
        int bBase = (kt >> 3) * 512 + k0;  // seg0=Bh, seg1=Bl
#pragma unroll
        for (int i = 0; i < 4; ++i) {
            int row = i * 32 + srow;
            gload16(Ah + (size_t)(bm + row) * 512 + k0 + kcol * 8,
                    As + i * 4096 + ldsoff);
            gload16(Bw + (size_t)(bn + row) * 1024 + bBase + kcol * 8,
                    Bs + i * 4096 + ldsoff);
        }
        __syncthreads();

#pragma unroll
        for (int kk = 0; kk < 2; ++kk) {
            bf16x8 af[4], bfr[4];
#pragma unroll
            for (int mf = 0; mf < 4; ++mf)
                af[mf] = *(const bf16x8*)(As + (wr*64 + mf*16 + (lane&15))*128
                                             + ((kk*4 + (lane>>4)) ^ (lane&7))*16);
#pragma unroll
            for (int nf = 0; nf < 4; ++nf)
                bfr[nf] = *(const bf16x8*)(Bs + (wc*64 + nf*16 + (lane&15))*128
                                              + ((kk*4 + (lane>>4)) ^ (lane&7))*16);
#pragma unroll
            for (int mf = 0; mf < 4; ++mf)
#pragma unroll
                for (int nf = 0; nf < 4; ++nf)
                    acc[mf][nf] = __builtin_amdgcn_mfma_f32_16x16x32_bf16(
                        af[mf], bfr[nf], acc[mf][nf], 0, 0, 0);
        }
        __syncthreads();
    }

    int r0 = bm + wr * 64 + (lane >> 4) * 4;
    int c0 = bn + wc * 64 + (lane & 15);
#pragma unroll
    for (int mf = 0; mf < 4; ++mf)
#pragma unroll
        for (int nf = 0; nf < 4; ++nf)
#pragma unroll
            for (int r = 0; r < 4; ++r) {
                float v = acc[mf][nf][r];
                unsigned short h = bf16rn(v);
                unsigned short l = bf16rn(v - bf16tof(h));
                size_t row = (size_t)(r0 + mf * 16 + r);
                Cs[row * 1024 + c0 + nf * 16] = h;
                Cs[row * 1024 + 512 + c0 + nf * 16] = l;
            }
}

// ---------------------------------------------------------------------------
// MFMA GAT layer: block = batch (512 thr / 8 waves), 4 blocks/CU target.
//  A: als/ald via vectorized bf16x8 loads; asrc/adst staged in LDS
//     (overlaid on the W_att region -- dead until phase B).
//  B: softmax -> W_att bf16 in LDS (swizzled; cols s=62,63 zeroed)
//  C: per head ch: C[62x128] = W*Xh + W*Xl via 16x16x32 MFMA; B-frag (X)
//     loaded directly from global.
//  APPLY=1: per-head +bias, relu -> bf16 H[V][512].
//  APPLY=0: acc NOT zeroed between heads (MFMA C accumulates) ->
//           head-mean + bias + relu -> f32 out[V][128]. No macc registers.
// ---------------------------------------------------------------------------
template <int APPLY>
__global__ __launch_bounds__(512, 8) void gat_aggM(
    const unsigned short* __restrict__ XL,   // [V+2][1024] hi|lo
    const float* __restrict__ asrc, const float* __restrict__ adst,
    const unsigned long long* __restrict__ maskT,
    const float* __restrict__ bias,
    void* __restrict__ outp)
{
    // LDS: [0,32768)  W_att [4][64 d][64 s] bf16 (swizzled)  -- phase B/C
    //      [0,2080)   av (8*65 f32)  \ overlaid, phase A only
    //      [2080,4160) dv            /
    //      [32768,33792) shs (256 f32), [33792,34816) shd
    __shared__ __align__(16) char lds[34816];
    float* av  = (float*)(lds);
    float* dv  = (float*)(lds + 2080);
    float* shs = (float*)(lds + 32768);
    float* shd = (float*)(lds + 33792);

    int b = blockIdx.x;
    int tid = threadIdx.x;
    int lane = tid & 63, w = tid >> 6;
    const unsigned short* base = XL + (size_t)b * N_ * 1024;

    // stage attention vectors (f32, padded stride 65)
    av[w * 65 + lane] = asrc[tid];
    dv[w * 65 + lane] = adst[tid];
    __syncthreads();

    // ---- phase A: als/ald, vectorized. thread = (s = tid>>3, sl = tid&7) ----
    {
        int s = tid >> 3, sl = tid & 7;   // sl: 64-col slice; head = sl>>1
        const unsigned short* xp = base + (size_t)s * 1024 + sl * 64;
        float ps = 0.f, pd = 0.f;
        union V8 { uint4 u; unsigned short s[8]; };
#pragma unroll
        for (int g = 0; g < 8; ++g) {
            V8 vh, vl;
            vh.u = *(const uint4*)(xp + g * 8);
            vl.u = *(const uint4*)(xp + 512 + g * 8);
            const float* avp = av + sl * 65 + g * 8;
            const float* dvp = dv + sl * 65 + g * 8;
#pragma unroll
            for (int j = 0; j < 8; ++j) {
                float xv = bf16tof(vh.s[j]) + bf16tof(vl.s[j]);
                ps += xv * avp[j];
                pd += xv * dvp[j];
            }
        }
        ps += __shfl_xor(ps, 1);          // combine the two slices of a head
        pd += __shfl_xor(pd, 1);
        if ((sl & 1) == 0) {
            shs[s * 4 + (sl >> 1)] = ps;
            shd[s * 4 + (sl >> 1)] = pd;
        }
    }
    __syncthreads();   // phase A done; av/dv dead from here

    // ---- phase B: masked softmax -> W_att (bf16, swizzled; s=62,63 -> 0) ----
    for (int t = w; t < 248; t += 8) {
        int d = t >> 2, h = t & 3;
        unsigned long long m = maskT[(size_t)b * N_ + d];
        bool valid = (lane < N_) && ((m >> lane) & 1ull);
        float a = -INFINITY;
        if (valid) {
            float raw = shs[lane * 4 + h] + shd[d * 4 + h];
            a = (raw > 0.f) ? raw : 0.2f * raw;
        }
        float mx = a;
#pragma unroll
        for (int off = 32; off; off >>= 1) mx = fmaxf(mx, __shfl_xor(mx, off));
        float ex = valid ? expf(a - mx) : 0.f;
        float sm = ex;
#pragma unroll
        for (int off = 32; off; off >>= 1) sm += __shfl_xor(sm, off);
        float wv = valid ? ex / sm : 0.f;
        int addr = h * 8192 + d * 128
                 + (((lane >> 3) ^ (d & 7)) << 4) + ((lane & 7) << 1);
        *(unsigned short*)(lds + addr) = bf16rn(wv);
    }
    __syncthreads();   // W ready; no LDS writes after this point

    int cc = lane & 15, lh = lane >> 4;

    union U8 { unsigned short s[8]; bf16x8 v; };

    f32x4 acc[4];
#pragma unroll
    for (int mf = 0; mf < 4; ++mf) acc[mf] = (f32x4){0.f, 0.f, 0.f, 0.f};

#pragma unroll
    for (int ch = 0; ch < 4; ++ch) {     // chunk == head
        if (APPLY == 1 && ch > 0) {
#pragma unroll
            for (int mf = 0; mf < 4; ++mf) acc[mf] = (f32x4){0.f, 0.f, 0.f, 0.f};
        }

        // this thread's column c and its s-rows lh*8..+7 (+32 for kk=1)
        const unsigned short* xp = base + (size_t)(lh * 8) * 1024
                                        + ch * 128 + w * 16 + cc;
#pragma unroll
        for (int kk = 0; kk < 2; ++kk) {
            U8 bh, bl;
#pragma unroll
            for (int j = 0; j < 8; ++j) {
                size_t o = (size_t)(kk * 32 + j) * 1024;
                bh.s[j] = xp[o];            // hi
                bl.s[j] = xp[o + 512];      // lo
            }
            bf16x8 af[4];
#pragma unroll
            for (int mf = 0; mf < 4; ++mf)
                af[mf] = *(const bf16x8*)(lds + ch * 8192
                              + (mf * 16 + cc) * 128
                              + (((kk * 4 + lh) ^ (cc & 7)) << 4));
#pragma unroll
            for (int mf = 0; mf < 4; ++mf) {
                acc[mf] = __builtin_amdgcn_mfma_f32_16x16x32_bf16(
                    af[mf], bh.v, acc[mf], 0, 0, 0);
                acc[mf] = __builtin_amdgcn_mfma_f32_16x16x32_bf16(
                    af[mf], bl.v, acc[mf], 0, 0, 0);
            }
        }

        if (APPLY == 1) {
            int c = ch * 128 + w * 16 + cc;
            float bc = bias[c];
            unsigned short* H = (unsigned short*)outp;
#pragma unroll
            for (int mf = 0; mf < 4; ++mf)
#pragma unroll
                for (int r = 0; r < 4; ++r) {
                    int d = mf * 16 + lh * 4 + r;
                    if (d < N_) {
                        float v = acc[mf][r] + bc;
                        v = v > 0.f ? v : 0.f;
                        H[(size_t)(b * N_ + d) * 512 + c] = bf16rn(v);
                    }
                }
        }
    }

    if (APPLY == 0) {
        // head-mean + bias + relu -> final f32 output [V][128]
        int c = w * 16 + cc;
        float bc = bias[c];
        float* outF = (float*)outp;
#pragma unroll
        for (int mf = 0; mf < 4; ++mf)
#pragma unroll
            for (int r = 0; r < 4; ++r) {
                int d = mf * 16 + lh * 4 + r;
                if (d < N_) {
                    float v = acc[mf][r] * 0.25f + bc;
                    outF[(size_t)(b * N_ + d) * 128 + c] = v > 0.f ? v : 0.f;
                }
            }
    }
}

// ---------------------------------------------------------------------------
extern "C" void kernel_launch(void* const* d_in, const int* in_sizes, int n_in,
                              void* d_out, int out_size, void* d_ws, size_t ws_size,
                              hipStream_t stream)
{
    const float* x    = (const float*)d_in[0];
    const float* W1   = (const float*)d_in[2];
    const float* W2   = (const float*)d_in[3];
    const float* bsp  = (const float*)d_in[4];
    const float* Vsp  = (const float*)d_in[5];
    const float* bnw  = (const float*)d_in[6];
    const float* bnb  = (const float*)d_in[7];
    const float* g1w  = (const float*)d_in[8];
    const float* g1as = (const float*)d_in[9];
    const float* g1ad = (const float*)d_in[10];
    const float* g1b  = (const float*)d_in[11];
    const float* g2w  = (const float*)d_in[12];
    const float* g2as = (const float*)d_in[13];
    const float* g2ad = (const float*)d_in[14];
    const float* g2b  = (const float*)d_in[15];
    float* out = (float*)d_out;

    char* ws = (char*)d_ws;
    size_t off = 0;
    auto alloc = [&](size_t bytes) -> void* {
        void* p = ws + off;
        off += (bytes + 255) & ~(size_t)255;
        return p;
    };
    float* S      = (float*)alloc((size_t)V_ * N_ * 4);          // 7.9 MB
    float* scale  = (float*)alloc(N_ * 4);
    float* shift  = (float*)alloc(N_ * 4);
    double* part  = (double*)alloc((size_t)N_ * 16 * 2 * 8);
    unsigned long long* maskT = (unsigned long long*)alloc((size_t)V_ * 8);
    unsigned short* A2  = (unsigned short*)alloc((size_t)V_ * 512 * 2);      // 32.5 MB
    unsigned short* Bw1 = (unsigned short*)alloc((size_t)512 * 1024 * 2);    // 1 MB
    unsigned short* Bw2 = (unsigned short*)alloc((size_t)512 * 1024 * 2);    // 1 MB
    unsigned short* XL  = (unsigned short*)alloc((size_t)(V_ + 2) * 1024 * 2); // 65 MB (+slack)
    unsigned short* H1  = (unsigned short*)alloc((size_t)V_ * 512 * 2);      // 32.5 MB

    zero_u64<<<(V_ + 255) / 256, 256, 0, stream>>>(maskT, V_);
    spatial_S<<<V_ / 4, 256, 0, stream>>>(x, W1, W2, bsp, Vsp, S, A2);
    bn_part<<<N_ * 16, 256, 0, stream>>>(S, part);
    bn_final<<<1, 64, 0, stream>>>(part, bnw, bnb, scale, shift);
    topk_mask<<<V_, 64, 0, stream>>>(S, scale, shift, maskT);

    split_pair<<<(512 * 128 + 255) / 256, 256, 0, stream>>>(g1w, Bw1, 512 * 128);
    split_pair<<<(512 * 128 + 255) / 256, 256, 0, stream>>>(g2w, Bw2, 512 * 128);

    dim3 gg(4, 248);
    gemm_bf16<<<gg, 256, 0, stream>>>(A2, Bw1, XL);
    gat_aggM<1><<<B_, 512, 0, stream>>>(XL, g1as, g1ad, maskT, g1b, H1);

    gemm_bf16<<<gg, 256, 0, stream>>>(H1, Bw2, XL);
    gat_aggM<0><<<B_, 512, 0, stream>>>(XL, g2as, g2ad, maskT, g2b, out);
}